// Round 1
// baseline (1758.883 us; speedup 1.0000x reference)
//
#include <hip/hip_runtime.h>

#ifndef __forceinline__
#define __forceinline__ inline __attribute__((always_inline))
#endif

constexpr float ACCEL_SCALE = 0.01f;
constexpr float MAX_VEL = 0.1f;
constexpr float MAX_POS = 1.0f;

// ---------------- kernel 1: degree count over dst ----------------
__global__ void deg_kernel(const int* __restrict__ dst, int E, int* __restrict__ deg) {
    int tid = blockIdx.x * blockDim.x + threadIdx.x;
    int stride = gridDim.x * blockDim.x;
    int n4 = E >> 2;
    const int4* d4 = (const int4*)dst;
    for (int k = tid; k < n4; k += stride) {
        int4 v = d4[k];
        atomicAdd(&deg[v.x], 1);
        atomicAdd(&deg[v.y], 1);
        atomicAdd(&deg[v.z], 1);
        atomicAdd(&deg[v.w], 1);
    }
    for (int k = (n4 << 2) + tid; k < E; k += stride)
        atomicAdd(&deg[dst[k]], 1);
}

// ---------------- kernel 2: per-node dinv + hs = (x@W)*dinv ----------------
__global__ void node_pre_kernel(const float* __restrict__ x, const float* __restrict__ W,
                                const int* __restrict__ deg, float* __restrict__ dinv,
                                float* __restrict__ hs, int n) {
    int i = blockIdx.x * blockDim.x + threadIdx.x;
    if (i >= n) return;
    float d = (float)(deg[i] + 1);   // +1 self-loop
    float di = rsqrtf(d);
    dinv[i] = di;
    const float* xr = x + (size_t)i * 5;
    float x0 = xr[0], x1 = xr[1], x2 = xr[2], x3 = xr[3], x4 = xr[4];
    // W is (5,2) row-major
    float h0 = x0 * W[0] + x1 * W[2] + x2 * W[4] + x3 * W[6] + x4 * W[8];
    float h1 = x0 * W[1] + x1 * W[3] + x2 * W[5] + x3 * W[7] + x4 * W[9];
    hs[2 * i]     = h0 * di;
    hs[2 * i + 1] = h1 * di;
}

// ---------------- kernel 3: edge scatter s[dst] += hs[src] ----------------
__global__ void scatter_kernel(const int* __restrict__ src, const int* __restrict__ dst,
                               int E, const float* __restrict__ hs, float* __restrict__ s) {
    int tid = blockIdx.x * blockDim.x + threadIdx.x;
    int stride = gridDim.x * blockDim.x;
    int n4 = E >> 2;
    const int4* s4 = (const int4*)src;
    const int4* d4 = (const int4*)dst;
    const float2* h2 = (const float2*)hs;
    for (int k = tid; k < n4; k += stride) {
        int4 sv = s4[k];
        int4 dv = d4[k];
        float2 m0 = h2[sv.x];
        float2 m1 = h2[sv.y];
        float2 m2 = h2[sv.z];
        float2 m3 = h2[sv.w];
        unsafeAtomicAdd(&s[2 * dv.x],     m0.x);
        unsafeAtomicAdd(&s[2 * dv.x + 1], m0.y);
        unsafeAtomicAdd(&s[2 * dv.y],     m1.x);
        unsafeAtomicAdd(&s[2 * dv.y + 1], m1.y);
        unsafeAtomicAdd(&s[2 * dv.z],     m2.x);
        unsafeAtomicAdd(&s[2 * dv.z + 1], m2.y);
        unsafeAtomicAdd(&s[2 * dv.w],     m3.x);
        unsafeAtomicAdd(&s[2 * dv.w + 1], m3.y);
    }
    for (int k = (n4 << 2) + tid; k < E; k += stride) {
        int sv = src[k];
        int dv = dst[k];
        float2 m = h2[sv];
        unsafeAtomicAdd(&s[2 * dv],     m.x);
        unsafeAtomicAdd(&s[2 * dv + 1], m.y);
    }
}

// ---------------- kernel 4: finalize ----------------
__global__ void finalize_kernel(const float* __restrict__ x, const float* __restrict__ s,
                                const float* __restrict__ hs, const float* __restrict__ dinv,
                                const float* __restrict__ b, float* __restrict__ out, int n) {
    int i = blockIdx.x * blockDim.x + threadIdx.x;
    if (i >= n) return;
    float di = dinv[i];
    const float2* s2 = (const float2*)s;
    const float2* h2 = (const float2*)hs;
    float2 sv = s2[i];
    float2 hv = h2[i];
    // conv = dinv*(edge_sum + self_msg) + b ; self term: hs[i]*dinv[i] = h*dinv^2
    float c0 = di * (sv.x + hv.x) + b[0];
    float c1 = di * (sv.y + hv.y) + b[1];
    float a0 = c0 * ACCEL_SCALE;
    float a1 = c1 * ACCEL_SCALE;
    const float* xr = x + (size_t)i * 5;
    float v0 = fminf(fmaxf(xr[2] + a0, -MAX_VEL), MAX_VEL);
    float v1 = fminf(fmaxf(xr[3] + a1, -MAX_VEL), MAX_VEL);
    float p0 = fminf(fmaxf(xr[0] + v0, -MAX_POS), MAX_POS);
    float p1 = fminf(fmaxf(xr[1] + v1, -MAX_POS), MAX_POS);
    float* o = out + (size_t)i * 5;
    o[0] = p0;
    o[1] = p1;
    o[2] = v0;
    o[3] = v1;
    o[4] = xr[4];
}

extern "C" void kernel_launch(void* const* d_in, const int* in_sizes, int n_in,
                              void* d_out, int out_size, void* d_ws, size_t ws_size,
                              hipStream_t stream) {
    const float* x    = (const float*)d_in[0];
    const int*   edge = (const int*)d_in[1];
    const float* W    = (const float*)d_in[2];
    const float* b    = (const float*)d_in[3];
    // d_in[4] = time_steps, fixed to 1 by setup_inputs

    int n = in_sizes[0] / 5;
    int E = in_sizes[1] / 2;
    const int* src = edge;
    const int* dst = edge + E;

    // workspace layout (floats): dinv[n] | hs[2n] | s[2n] | deg[n] (as int)
    float* dinv = (float*)d_ws;
    float* hs   = dinv + n;
    float* s    = hs + 2 * (size_t)n;
    int*   deg  = (int*)(s + 2 * (size_t)n);

    hipMemsetAsync(deg, 0, (size_t)n * sizeof(int), stream);
    hipMemsetAsync(s,   0, (size_t)n * 2 * sizeof(float), stream);

    const int BLK = 256;
    int edge_blocks = 4096;               // grid-stride over E/4 packs
    int node_blocks = (n + BLK - 1) / BLK;

    deg_kernel<<<edge_blocks, BLK, 0, stream>>>(dst, E, deg);
    node_pre_kernel<<<node_blocks, BLK, 0, stream>>>(x, W, deg, dinv, hs, n);
    scatter_kernel<<<edge_blocks, BLK, 0, stream>>>(src, dst, E, hs, s);
    finalize_kernel<<<node_blocks, BLK, 0, stream>>>(x, s, hs, dinv, b, d_out ? (float*)d_out : nullptr, n);
}

// Round 2
// 366.011 us; speedup vs baseline: 4.8055x; 4.8055x over previous
//
#include <hip/hip_runtime.h>

constexpr float ACCEL_SCALE = 0.01f;
constexpr float MAX_VEL = 0.1f;
constexpr float MAX_POS = 1.0f;

constexpr int BSHIFT = 8;           // 256 nodes per bucket
constexpr int BSIZE  = 1 << BSHIFT;
constexpr int NBMAX  = 1024;        // max buckets supported by fast path

// ============================ fast path ============================

// pass 1: global bucket histogram (per-block LDS hist, then merge)
__global__ void hist_kernel(const int* __restrict__ dst, int E, int NB,
                            int* __restrict__ ghist) {
    __shared__ int lh[NBMAX];
    for (int t = threadIdx.x; t < NB; t += blockDim.x) lh[t] = 0;
    __syncthreads();
    int chunk = ((E + gridDim.x - 1) / gridDim.x + 3) & ~3;
    int start = blockIdx.x * chunk;
    int end = min(start + chunk, E);
    if (start < end) {
        int nvec = (end - start) >> 2;
        const int4* d4 = (const int4*)(dst + start);
        for (int k = threadIdx.x; k < nvec; k += blockDim.x) {
            int4 v = d4[k];
            atomicAdd(&lh[v.x >> BSHIFT], 1);
            atomicAdd(&lh[v.y >> BSHIFT], 1);
            atomicAdd(&lh[v.z >> BSHIFT], 1);
            atomicAdd(&lh[v.w >> BSHIFT], 1);
        }
        for (int i = start + (nvec << 2) + threadIdx.x; i < end; i += blockDim.x)
            atomicAdd(&lh[dst[i] >> BSHIFT], 1);
    }
    __syncthreads();
    for (int t = threadIdx.x; t < NB; t += blockDim.x) {
        int c = lh[t];
        if (c) atomicAdd(&ghist[t], c);
    }
}

// pass 2: exclusive scan over NB (<=1024) bucket counts, one block
__global__ void scan_kernel(const int* __restrict__ ghist, int NB,
                            int* __restrict__ gcursor) {
    __shared__ int tmp[NBMAX];
    int tid = threadIdx.x;
    int v = (tid < NB) ? ghist[tid] : 0;
    tmp[tid] = v;
    __syncthreads();
    for (int off = 1; off < NBMAX; off <<= 1) {
        int t = (tid >= off) ? tmp[tid - off] : 0;
        __syncthreads();
        tmp[tid] += t;
        __syncthreads();
    }
    if (tid < NB) gcursor[tid] = tmp[tid] - v;   // exclusive
}

// pass 3: bin edges by dst-bucket; store (src<<8)|local_dst as u32
__global__ void scatter_pack_kernel(const int* __restrict__ src, const int* __restrict__ dst,
                                    int E, int NB, int* __restrict__ gcursor,
                                    unsigned int* __restrict__ packed) {
    __shared__ int lh[NBMAX];
    for (int t = threadIdx.x; t < NB; t += blockDim.x) lh[t] = 0;
    __syncthreads();
    int chunk = ((E + gridDim.x - 1) / gridDim.x + 3) & ~3;
    int start = blockIdx.x * chunk;
    int end = min(start + chunk, E);
    int nvec = (start < end) ? ((end - start) >> 2) : 0;
    const int4* d4 = (const int4*)(dst + start);
    const int4* s4 = (const int4*)(src + start);
    // phase 1: local histogram
    if (start < end) {
        for (int k = threadIdx.x; k < nvec; k += blockDim.x) {
            int4 v = d4[k];
            atomicAdd(&lh[v.x >> BSHIFT], 1);
            atomicAdd(&lh[v.y >> BSHIFT], 1);
            atomicAdd(&lh[v.z >> BSHIFT], 1);
            atomicAdd(&lh[v.w >> BSHIFT], 1);
        }
        for (int i = start + (nvec << 2) + threadIdx.x; i < end; i += blockDim.x)
            atomicAdd(&lh[dst[i] >> BSHIFT], 1);
    }
    __syncthreads();
    // phase 2: reserve global ranges; lh[t] becomes running cursor
    for (int t = threadIdx.x; t < NB; t += blockDim.x) {
        int c = lh[t];
        lh[t] = c ? atomicAdd(&gcursor[t], c) : 0;
    }
    __syncthreads();
    // phase 3: write packed edges
    if (start < end) {
        for (int k = threadIdx.x; k < nvec; k += blockDim.x) {
            int4 dv = d4[k];
            int4 sv = s4[k];
            int p;
            p = atomicAdd(&lh[dv.x >> BSHIFT], 1);
            packed[p] = ((unsigned)sv.x << BSHIFT) | (unsigned)(dv.x & (BSIZE - 1));
            p = atomicAdd(&lh[dv.y >> BSHIFT], 1);
            packed[p] = ((unsigned)sv.y << BSHIFT) | (unsigned)(dv.y & (BSIZE - 1));
            p = atomicAdd(&lh[dv.z >> BSHIFT], 1);
            packed[p] = ((unsigned)sv.z << BSHIFT) | (unsigned)(dv.z & (BSIZE - 1));
            p = atomicAdd(&lh[dv.w >> BSHIFT], 1);
            packed[p] = ((unsigned)sv.w << BSHIFT) | (unsigned)(dv.w & (BSIZE - 1));
        }
        for (int i = start + (nvec << 2) + threadIdx.x; i < end; i += blockDim.x) {
            int dv = dst[i], sv = src[i];
            int p = atomicAdd(&lh[dv >> BSHIFT], 1);
            packed[p] = ((unsigned)sv << BSHIFT) | (unsigned)(dv & (BSIZE - 1));
        }
    }
}

// pass 4: per-bucket degree count -> dinv (one block per bucket)
__global__ void dinv_kernel(const unsigned int* __restrict__ packed,
                            const int* __restrict__ gcursor, const int* __restrict__ ghist,
                            int n, float* __restrict__ dinv) {
    __shared__ int cnt[BSIZE];
    int bk = blockIdx.x;
    cnt[threadIdx.x] = 0;
    __syncthreads();
    int end = gcursor[bk];          // after pass 3, gcursor[bk] == segment end
    int start = end - ghist[bk];
    for (int i = start + threadIdx.x; i < end; i += blockDim.x)
        atomicAdd(&cnt[packed[i] & (BSIZE - 1)], 1);
    __syncthreads();
    int node = (bk << BSHIFT) + threadIdx.x;
    if (node < n)
        dinv[node] = rsqrtf((float)(cnt[threadIdx.x] + 1));   // +1 self loop
}

// pass 5: hs = (x @ W) * dinv
__global__ void node_pre_kernel(const float* __restrict__ x, const float* __restrict__ W,
                                const float* __restrict__ dinv, float* __restrict__ hs, int n) {
    int i = blockIdx.x * blockDim.x + threadIdx.x;
    if (i >= n) return;
    const float* xr = x + (size_t)i * 5;
    float x0 = xr[0], x1 = xr[1], x2 = xr[2], x3 = xr[3], x4 = xr[4];
    float h0 = x0 * W[0] + x1 * W[2] + x2 * W[4] + x3 * W[6] + x4 * W[8];
    float h1 = x0 * W[1] + x1 * W[3] + x2 * W[5] + x3 * W[7] + x4 * W[9];
    float di = dinv[i];
    hs[2 * i]     = h0 * di;
    hs[2 * i + 1] = h1 * di;
}

// pass 6: per-bucket LDS accumulate + fused finalize (one block per bucket)
__global__ void acc_finalize_kernel(const unsigned int* __restrict__ packed,
                                    const int* __restrict__ gcursor, const int* __restrict__ ghist,
                                    const float* __restrict__ hs, const float* __restrict__ dinv,
                                    const float* __restrict__ x, const float* __restrict__ b,
                                    float* __restrict__ out, int n) {
    __shared__ float accx[BSIZE];
    __shared__ float accy[BSIZE];
    int bk = blockIdx.x;
    accx[threadIdx.x] = 0.f;
    accy[threadIdx.x] = 0.f;
    __syncthreads();
    int end = gcursor[bk];
    int start = end - ghist[bk];
    const float2* h2 = (const float2*)hs;
    for (int i = start + threadIdx.x; i < end; i += blockDim.x) {
        unsigned int p = packed[i];
        float2 m = h2[p >> BSHIFT];
        int ld = p & (BSIZE - 1);
        unsafeAtomicAdd(&accx[ld], m.x);
        unsafeAtomicAdd(&accy[ld], m.y);
    }
    __syncthreads();
    int node = (bk << BSHIFT) + threadIdx.x;
    if (node >= n) return;
    float di = dinv[node];
    float2 hv = h2[node];
    float c0 = di * (accx[threadIdx.x] + hv.x) + b[0];
    float c1 = di * (accy[threadIdx.x] + hv.y) + b[1];
    float a0 = c0 * ACCEL_SCALE;
    float a1 = c1 * ACCEL_SCALE;
    const float* xr = x + (size_t)node * 5;
    float v0 = fminf(fmaxf(xr[2] + a0, -MAX_VEL), MAX_VEL);
    float v1 = fminf(fmaxf(xr[3] + a1, -MAX_VEL), MAX_VEL);
    float p0 = fminf(fmaxf(xr[0] + v0, -MAX_POS), MAX_POS);
    float p1 = fminf(fmaxf(xr[1] + v1, -MAX_POS), MAX_POS);
    float* o = out + (size_t)node * 5;
    o[0] = p0; o[1] = p1; o[2] = v0; o[3] = v1; o[4] = xr[4];
}

// ============================ fallback path (round-1 atomic pipeline) ============================

__global__ void fb_deg_kernel(const int* __restrict__ dst, int E, int* __restrict__ deg) {
    int tid = blockIdx.x * blockDim.x + threadIdx.x;
    int stride = gridDim.x * blockDim.x;
    int n4 = E >> 2;
    const int4* d4 = (const int4*)dst;
    for (int k = tid; k < n4; k += stride) {
        int4 v = d4[k];
        atomicAdd(&deg[v.x], 1); atomicAdd(&deg[v.y], 1);
        atomicAdd(&deg[v.z], 1); atomicAdd(&deg[v.w], 1);
    }
    for (int k = (n4 << 2) + tid; k < E; k += stride) atomicAdd(&deg[dst[k]], 1);
}

__global__ void fb_node_pre_kernel(const float* __restrict__ x, const float* __restrict__ W,
                                   const int* __restrict__ deg, float* __restrict__ dinv,
                                   float* __restrict__ hs, int n) {
    int i = blockIdx.x * blockDim.x + threadIdx.x;
    if (i >= n) return;
    float di = rsqrtf((float)(deg[i] + 1));
    dinv[i] = di;
    const float* xr = x + (size_t)i * 5;
    float x0 = xr[0], x1 = xr[1], x2 = xr[2], x3 = xr[3], x4 = xr[4];
    float h0 = x0 * W[0] + x1 * W[2] + x2 * W[4] + x3 * W[6] + x4 * W[8];
    float h1 = x0 * W[1] + x1 * W[3] + x2 * W[5] + x3 * W[7] + x4 * W[9];
    hs[2 * i] = h0 * di;
    hs[2 * i + 1] = h1 * di;
}

__global__ void fb_scatter_kernel(const int* __restrict__ src, const int* __restrict__ dst,
                                  int E, const float* __restrict__ hs, float* __restrict__ s) {
    int tid = blockIdx.x * blockDim.x + threadIdx.x;
    int stride = gridDim.x * blockDim.x;
    const float2* h2 = (const float2*)hs;
    for (int k = tid; k < E; k += stride) {
        int sv = src[k], dv = dst[k];
        float2 m = h2[sv];
        unsafeAtomicAdd(&s[2 * dv], m.x);
        unsafeAtomicAdd(&s[2 * dv + 1], m.y);
    }
}

__global__ void fb_finalize_kernel(const float* __restrict__ x, const float* __restrict__ s,
                                   const float* __restrict__ hs, const float* __restrict__ dinv,
                                   const float* __restrict__ b, float* __restrict__ out, int n) {
    int i = blockIdx.x * blockDim.x + threadIdx.x;
    if (i >= n) return;
    float di = dinv[i];
    const float2* s2 = (const float2*)s;
    const float2* h2 = (const float2*)hs;
    float2 sv = s2[i];
    float2 hv = h2[i];
    float c0 = di * (sv.x + hv.x) + b[0];
    float c1 = di * (sv.y + hv.y) + b[1];
    float a0 = c0 * ACCEL_SCALE, a1 = c1 * ACCEL_SCALE;
    const float* xr = x + (size_t)i * 5;
    float v0 = fminf(fmaxf(xr[2] + a0, -MAX_VEL), MAX_VEL);
    float v1 = fminf(fmaxf(xr[3] + a1, -MAX_VEL), MAX_VEL);
    float p0 = fminf(fmaxf(xr[0] + v0, -MAX_POS), MAX_POS);
    float p1 = fminf(fmaxf(xr[1] + v1, -MAX_POS), MAX_POS);
    float* o = out + (size_t)i * 5;
    o[0] = p0; o[1] = p1; o[2] = v0; o[3] = v1; o[4] = xr[4];
}

extern "C" void kernel_launch(void* const* d_in, const int* in_sizes, int n_in,
                              void* d_out, int out_size, void* d_ws, size_t ws_size,
                              hipStream_t stream) {
    const float* x    = (const float*)d_in[0];
    const int*   edge = (const int*)d_in[1];
    const float* W    = (const float*)d_in[2];
    const float* b    = (const float*)d_in[3];

    int n = in_sizes[0] / 5;
    int E = in_sizes[1] / 2;
    const int* src = edge;
    const int* dst = edge + E;

    const int BLK = 256;
    int node_blocks = (n + BLK - 1) / BLK;
    int NB = (n + BSIZE - 1) >> BSHIFT;

    // fast-path workspace: dinv[n] | hs[2n] | ghist[NBMAX] | gcursor[NBMAX] | packed[E]
    size_t needed = ((size_t)3 * n + 2 * NBMAX) * 4 + (size_t)E * 4;

    if (NB <= NBMAX && ws_size >= needed) {
        float* dinv = (float*)d_ws;
        float* hs   = dinv + n;
        int* ghist  = (int*)(hs + 2 * (size_t)n);
        int* gcursor = ghist + NBMAX;
        unsigned int* packed = (unsigned int*)(gcursor + NBMAX);

        hipMemsetAsync(ghist, 0, NBMAX * sizeof(int), stream);

        hist_kernel<<<512, BLK, 0, stream>>>(dst, E, NB, ghist);
        scan_kernel<<<1, NBMAX, 0, stream>>>(ghist, NB, gcursor);
        scatter_pack_kernel<<<512, BLK, 0, stream>>>(src, dst, E, NB, gcursor, packed);
        dinv_kernel<<<NB, BSIZE, 0, stream>>>(packed, gcursor, ghist, n, dinv);
        node_pre_kernel<<<node_blocks, BLK, 0, stream>>>(x, W, dinv, hs, n);
        acc_finalize_kernel<<<NB, BSIZE, 0, stream>>>(packed, gcursor, ghist, hs, dinv,
                                                      x, b, (float*)d_out, n);
    } else {
        // fallback: round-1 atomic pipeline (needs 6n floats)
        float* dinv = (float*)d_ws;
        float* hs   = dinv + n;
        float* s    = hs + 2 * (size_t)n;
        int*   deg  = (int*)(s + 2 * (size_t)n);
        hipMemsetAsync(deg, 0, (size_t)n * sizeof(int), stream);
        hipMemsetAsync(s,   0, (size_t)n * 2 * sizeof(float), stream);
        fb_deg_kernel<<<4096, BLK, 0, stream>>>(dst, E, deg);
        fb_node_pre_kernel<<<node_blocks, BLK, 0, stream>>>(x, W, deg, dinv, hs, n);
        fb_scatter_kernel<<<4096, BLK, 0, stream>>>(src, dst, E, hs, s);
        fb_finalize_kernel<<<node_blocks, BLK, 0, stream>>>(x, s, hs, dinv, b, (float*)d_out, n);
    }
}

// Round 3
// 284.215 us; speedup vs baseline: 6.1886x; 1.2878x over previous
//
#include <hip/hip_runtime.h>

constexpr float ACCEL_SCALE = 0.01f;
constexpr float MAX_VEL = 0.1f;
constexpr float MAX_POS = 1.0f;

// ============================ PATH A: block-local bucket sort ============================
constexpr int ABSHIFT = 10;           // 1024 nodes per bucket
constexpr int ABSIZE  = 1 << ABSHIFT;
constexpr int ANBMAX  = 256;          // scan width; requires NB < ANBMAX
constexpr int ANBLK   = 1024;         // scatter blocks
constexpr int SPLITD  = 8;            // deg-count blocks per bucket
constexpr int SPLITA  = 4;            // acc blocks per bucket

// One block sorts its own contiguous edge chunk by dst-bucket, writes packed
// (src<<10 | local_dst) into its own output range, plus per-bucket offsets tab.
__global__ __launch_bounds__(256) void a_scatter_kernel(
    const int* __restrict__ src, const int* __restrict__ dst,
    int E, int NB, int chunk,
    unsigned* __restrict__ tab, unsigned* __restrict__ packed)
{
    __shared__ int cnt[ANBMAX];
    __shared__ int tmp[ANBMAX];
    __shared__ int cur[ANBMAX];
    int tid = threadIdx.x;
    long long cs64 = (long long)blockIdx.x * chunk;
    int cs = (cs64 > E) ? E : (int)cs64;
    int ce = min(cs + chunk, E);

    cnt[tid] = 0;
    __syncthreads();

    int nv = (ce - cs) >> 2;
    const int4* d4 = (const int4*)(dst + cs);
    // phase 1: histogram
    for (int k = tid; k < nv; k += 256) {
        int4 v = d4[k];
        atomicAdd(&cnt[v.x >> ABSHIFT], 1);
        atomicAdd(&cnt[v.y >> ABSHIFT], 1);
        atomicAdd(&cnt[v.z >> ABSHIFT], 1);
        atomicAdd(&cnt[v.w >> ABSHIFT], 1);
    }
    for (int i = cs + (nv << 2) + tid; i < ce; i += 256)
        atomicAdd(&cnt[dst[i] >> ABSHIFT], 1);
    __syncthreads();

    // phase 2: exclusive scan over ANBMAX entries (Hillis-Steele)
    int v = cnt[tid];
    tmp[tid] = v;
    __syncthreads();
    for (int off = 1; off < ANBMAX; off <<= 1) {
        int t = (tid >= off) ? tmp[tid - off] : 0;
        __syncthreads();
        tmp[tid] += t;
        __syncthreads();
    }
    int base = tmp[tid] - v;      // exclusive prefix; for tid>=NB equals chunk total
    cur[tid] = base;
    if (tid <= NB)
        tab[(size_t)blockIdx.x * (NB + 1) + tid] = (unsigned)base;
    __syncthreads();

    // phase 3: scatter into own range (re-read edges)
    const int4* s4 = (const int4*)(src + cs);
    for (int k = tid; k < nv; k += 256) {
        int4 dv = d4[k];
        int4 sv = s4[k];
        int p;
        p = atomicAdd(&cur[dv.x >> ABSHIFT], 1);
        packed[cs + p] = ((unsigned)sv.x << ABSHIFT) | (unsigned)(dv.x & (ABSIZE - 1));
        p = atomicAdd(&cur[dv.y >> ABSHIFT], 1);
        packed[cs + p] = ((unsigned)sv.y << ABSHIFT) | (unsigned)(dv.y & (ABSIZE - 1));
        p = atomicAdd(&cur[dv.z >> ABSHIFT], 1);
        packed[cs + p] = ((unsigned)sv.z << ABSHIFT) | (unsigned)(dv.z & (ABSIZE - 1));
        p = atomicAdd(&cur[dv.w >> ABSHIFT], 1);
        packed[cs + p] = ((unsigned)sv.w << ABSHIFT) | (unsigned)(dv.w & (ABSIZE - 1));
    }
    for (int i = cs + (nv << 2) + tid; i < ce; i += 256) {
        int dvv = dst[i], svv = src[i];
        int p = atomicAdd(&cur[dvv >> ABSHIFT], 1);
        packed[cs + p] = ((unsigned)svv << ABSHIFT) | (unsigned)(dvv & (ABSIZE - 1));
    }
}

// per-(bucket,split) degree count via LDS counters -> pdeg partials (no atomics)
__global__ __launch_bounds__(256) void a_deg_kernel(
    const unsigned* __restrict__ packed, const unsigned* __restrict__ tab,
    int E, int NB, int chunk, int n, int* __restrict__ pdeg)
{
    __shared__ int cnt[ABSIZE];
    int b = blockIdx.x >> 3;          // SPLITD == 8
    int s = blockIdx.x & 7;
    for (int t = threadIdx.x; t < ABSIZE; t += 256) cnt[t] = 0;
    __syncthreads();
    int wave = threadIdx.x >> 6, lane = threadIdx.x & 63;
    const int perSplit = ANBLK / SPLITD;      // 128 slices
    int j0 = s * perSplit;
    for (int j = j0 + wave; j < j0 + perSplit; j += 4) {
        long long cs64 = (long long)j * chunk;
        int cs = (cs64 > E) ? E : (int)cs64;
        const unsigned* trow = tab + (size_t)j * (NB + 1) + b;
        unsigned t0 = trow[0], t1 = trow[1];
        for (unsigned i = t0 + lane; i < t1; i += 64)
            atomicAdd(&cnt[packed[cs + i] & (ABSIZE - 1)], 1);
    }
    __syncthreads();
    int nb0 = b << ABSHIFT;
    for (int t = threadIdx.x; t < ABSIZE; t += 256) {
        int node = nb0 + t;
        if (node < n) pdeg[(size_t)s * n + node] = cnt[t];
    }
}

__global__ void a_dinv_kernel(const int* __restrict__ pdeg, int n, float* __restrict__ dinv) {
    int i = blockIdx.x * blockDim.x + threadIdx.x;
    if (i >= n) return;
    int d = 1;   // self loop
    for (int s = 0; s < SPLITD; ++s) d += pdeg[(size_t)s * n + i];
    dinv[i] = rsqrtf((float)d);
}

// hs = (x @ W) * dinv
__global__ void node_pre_kernel(const float* __restrict__ x, const float* __restrict__ W,
                                const float* __restrict__ dinv, float* __restrict__ hs, int n) {
    int i = blockIdx.x * blockDim.x + threadIdx.x;
    if (i >= n) return;
    const float* xr = x + (size_t)i * 5;
    float x0 = xr[0], x1 = xr[1], x2 = xr[2], x3 = xr[3], x4 = xr[4];
    float h0 = x0 * W[0] + x1 * W[2] + x2 * W[4] + x3 * W[6] + x4 * W[8];
    float h1 = x0 * W[1] + x1 * W[3] + x2 * W[5] + x3 * W[7] + x4 * W[9];
    float di = dinv[i];
    hs[2 * i]     = h0 * di;
    hs[2 * i + 1] = h1 * di;
}

// per-(bucket,split) LDS accumulate -> ps partials (no global atomics)
__global__ __launch_bounds__(256) void a_acc_kernel(
    const unsigned* __restrict__ packed, const unsigned* __restrict__ tab,
    const float* __restrict__ hs, int E, int NB, int chunk, int n,
    float2* __restrict__ ps)
{
    __shared__ float accx[ABSIZE];
    __shared__ float accy[ABSIZE];
    int b = blockIdx.x >> 2;          // SPLITA == 4
    int s = blockIdx.x & 3;
    for (int t = threadIdx.x; t < ABSIZE; t += 256) { accx[t] = 0.f; accy[t] = 0.f; }
    __syncthreads();
    int wave = threadIdx.x >> 6, lane = threadIdx.x & 63;
    const int perSplit = ANBLK / SPLITA;      // 256 slices
    int j0 = s * perSplit;
    const float2* h2 = (const float2*)hs;
    for (int j = j0 + wave; j < j0 + perSplit; j += 4) {
        long long cs64 = (long long)j * chunk;
        int cs = (cs64 > E) ? E : (int)cs64;
        const unsigned* trow = tab + (size_t)j * (NB + 1) + b;
        unsigned t0 = trow[0], t1 = trow[1];
        for (unsigned i = t0 + lane; i < t1; i += 64) {
            unsigned p = packed[cs + i];
            float2 m = h2[p >> ABSHIFT];
            int ld = p & (ABSIZE - 1);
            unsafeAtomicAdd(&accx[ld], m.x);
            unsafeAtomicAdd(&accy[ld], m.y);
        }
    }
    __syncthreads();
    int nb0 = b << ABSHIFT;
    for (int t = threadIdx.x; t < ABSIZE; t += 256) {
        int node = nb0 + t;
        if (node < n) ps[(size_t)s * n + node] = make_float2(accx[t], accy[t]);
    }
}

__global__ void a_final_kernel(const float* __restrict__ x, const float2* __restrict__ ps,
                               const float* __restrict__ hs, const float* __restrict__ dinv,
                               const float* __restrict__ b, float* __restrict__ out, int n) {
    int i = blockIdx.x * blockDim.x + threadIdx.x;
    if (i >= n) return;
    float sx = 0.f, sy = 0.f;
    for (int s = 0; s < SPLITA; ++s) {
        float2 v = ps[(size_t)s * n + i];
        sx += v.x; sy += v.y;
    }
    const float2* h2 = (const float2*)hs;
    float di = dinv[i];
    float2 hv = h2[i];
    float c0 = di * (sx + hv.x) + b[0];
    float c1 = di * (sy + hv.y) + b[1];
    float a0 = c0 * ACCEL_SCALE;
    float a1 = c1 * ACCEL_SCALE;
    const float* xr = x + (size_t)i * 5;
    float v0 = fminf(fmaxf(xr[2] + a0, -MAX_VEL), MAX_VEL);
    float v1 = fminf(fmaxf(xr[3] + a1, -MAX_VEL), MAX_VEL);
    float p0 = fminf(fmaxf(xr[0] + v0, -MAX_POS), MAX_POS);
    float p1 = fminf(fmaxf(xr[1] + v1, -MAX_POS), MAX_POS);
    float* o = out + (size_t)i * 5;
    o[0] = p0; o[1] = p1; o[2] = v0; o[3] = v1; o[4] = xr[4];
}

// ============================ PATH B: round-2 pipeline (fallback) ============================
constexpr int BSHIFT = 8;
constexpr int BSIZE  = 1 << BSHIFT;
constexpr int NBMAX  = 1024;

__global__ void hist_kernel(const int* __restrict__ dst, int E, int NB,
                            int* __restrict__ ghist) {
    __shared__ int lh[NBMAX];
    for (int t = threadIdx.x; t < NB; t += blockDim.x) lh[t] = 0;
    __syncthreads();
    int chunk = ((E + gridDim.x - 1) / gridDim.x + 3) & ~3;
    int start = blockIdx.x * chunk;
    int end = min(start + chunk, E);
    if (start < end) {
        int nvec = (end - start) >> 2;
        const int4* d4 = (const int4*)(dst + start);
        for (int k = threadIdx.x; k < nvec; k += blockDim.x) {
            int4 v = d4[k];
            atomicAdd(&lh[v.x >> BSHIFT], 1);
            atomicAdd(&lh[v.y >> BSHIFT], 1);
            atomicAdd(&lh[v.z >> BSHIFT], 1);
            atomicAdd(&lh[v.w >> BSHIFT], 1);
        }
        for (int i = start + (nvec << 2) + threadIdx.x; i < end; i += blockDim.x)
            atomicAdd(&lh[dst[i] >> BSHIFT], 1);
    }
    __syncthreads();
    for (int t = threadIdx.x; t < NB; t += blockDim.x) {
        int c = lh[t];
        if (c) atomicAdd(&ghist[t], c);
    }
}

__global__ void scan_kernel(const int* __restrict__ ghist, int NB,
                            int* __restrict__ gcursor) {
    __shared__ int tmp[NBMAX];
    int tid = threadIdx.x;
    int v = (tid < NB) ? ghist[tid] : 0;
    tmp[tid] = v;
    __syncthreads();
    for (int off = 1; off < NBMAX; off <<= 1) {
        int t = (tid >= off) ? tmp[tid - off] : 0;
        __syncthreads();
        tmp[tid] += t;
        __syncthreads();
    }
    if (tid < NB) gcursor[tid] = tmp[tid] - v;
}

__global__ void scatter_pack_kernel(const int* __restrict__ src, const int* __restrict__ dst,
                                    int E, int NB, int* __restrict__ gcursor,
                                    unsigned int* __restrict__ packed) {
    __shared__ int lh[NBMAX];
    for (int t = threadIdx.x; t < NB; t += blockDim.x) lh[t] = 0;
    __syncthreads();
    int chunk = ((E + gridDim.x - 1) / gridDim.x + 3) & ~3;
    int start = blockIdx.x * chunk;
    int end = min(start + chunk, E);
    int nvec = (start < end) ? ((end - start) >> 2) : 0;
    const int4* d4 = (const int4*)(dst + start);
    const int4* s4 = (const int4*)(src + start);
    if (start < end) {
        for (int k = threadIdx.x; k < nvec; k += blockDim.x) {
            int4 v = d4[k];
            atomicAdd(&lh[v.x >> BSHIFT], 1);
            atomicAdd(&lh[v.y >> BSHIFT], 1);
            atomicAdd(&lh[v.z >> BSHIFT], 1);
            atomicAdd(&lh[v.w >> BSHIFT], 1);
        }
        for (int i = start + (nvec << 2) + threadIdx.x; i < end; i += blockDim.x)
            atomicAdd(&lh[dst[i] >> BSHIFT], 1);
    }
    __syncthreads();
    for (int t = threadIdx.x; t < NB; t += blockDim.x) {
        int c = lh[t];
        lh[t] = c ? atomicAdd(&gcursor[t], c) : 0;
    }
    __syncthreads();
    if (start < end) {
        for (int k = threadIdx.x; k < nvec; k += blockDim.x) {
            int4 dv = d4[k];
            int4 sv = s4[k];
            int p;
            p = atomicAdd(&lh[dv.x >> BSHIFT], 1);
            packed[p] = ((unsigned)sv.x << BSHIFT) | (unsigned)(dv.x & (BSIZE - 1));
            p = atomicAdd(&lh[dv.y >> BSHIFT], 1);
            packed[p] = ((unsigned)sv.y << BSHIFT) | (unsigned)(dv.y & (BSIZE - 1));
            p = atomicAdd(&lh[dv.z >> BSHIFT], 1);
            packed[p] = ((unsigned)sv.z << BSHIFT) | (unsigned)(dv.z & (BSIZE - 1));
            p = atomicAdd(&lh[dv.w >> BSHIFT], 1);
            packed[p] = ((unsigned)sv.w << BSHIFT) | (unsigned)(dv.w & (BSIZE - 1));
        }
        for (int i = start + (nvec << 2) + threadIdx.x; i < end; i += blockDim.x) {
            int dv = dst[i], sv = src[i];
            int p = atomicAdd(&lh[dv >> BSHIFT], 1);
            packed[p] = ((unsigned)sv << BSHIFT) | (unsigned)(dv & (BSIZE - 1));
        }
    }
}

__global__ void dinv_kernel(const unsigned int* __restrict__ packed,
                            const int* __restrict__ gcursor, const int* __restrict__ ghist,
                            int n, float* __restrict__ dinv) {
    __shared__ int cnt[BSIZE];
    int bk = blockIdx.x;
    cnt[threadIdx.x] = 0;
    __syncthreads();
    int end = gcursor[bk];
    int start = end - ghist[bk];
    for (int i = start + threadIdx.x; i < end; i += blockDim.x)
        atomicAdd(&cnt[packed[i] & (BSIZE - 1)], 1);
    __syncthreads();
    int node = (bk << BSHIFT) + threadIdx.x;
    if (node < n)
        dinv[node] = rsqrtf((float)(cnt[threadIdx.x] + 1));
}

__global__ void acc_finalize_kernel(const unsigned int* __restrict__ packed,
                                    const int* __restrict__ gcursor, const int* __restrict__ ghist,
                                    const float* __restrict__ hs, const float* __restrict__ dinv,
                                    const float* __restrict__ x, const float* __restrict__ b,
                                    float* __restrict__ out, int n) {
    __shared__ float accx[BSIZE];
    __shared__ float accy[BSIZE];
    int bk = blockIdx.x;
    accx[threadIdx.x] = 0.f;
    accy[threadIdx.x] = 0.f;
    __syncthreads();
    int end = gcursor[bk];
    int start = end - ghist[bk];
    const float2* h2 = (const float2*)hs;
    for (int i = start + threadIdx.x; i < end; i += blockDim.x) {
        unsigned int p = packed[i];
        float2 m = h2[p >> BSHIFT];
        int ld = p & (BSIZE - 1);
        unsafeAtomicAdd(&accx[ld], m.x);
        unsafeAtomicAdd(&accy[ld], m.y);
    }
    __syncthreads();
    int node = (bk << BSHIFT) + threadIdx.x;
    if (node >= n) return;
    float di = dinv[node];
    float2 hv = h2[node];
    float c0 = di * (accx[threadIdx.x] + hv.x) + b[0];
    float c1 = di * (accy[threadIdx.x] + hv.y) + b[1];
    float a0 = c0 * ACCEL_SCALE;
    float a1 = c1 * ACCEL_SCALE;
    const float* xr = x + (size_t)node * 5;
    float v0 = fminf(fmaxf(xr[2] + a0, -MAX_VEL), MAX_VEL);
    float v1 = fminf(fmaxf(xr[3] + a1, -MAX_VEL), MAX_VEL);
    float p0 = fminf(fmaxf(xr[0] + v0, -MAX_POS), MAX_POS);
    float p1 = fminf(fmaxf(xr[1] + v1, -MAX_POS), MAX_POS);
    float* o = out + (size_t)node * 5;
    o[0] = p0; o[1] = p1; o[2] = v0; o[3] = v1; o[4] = xr[4];
}

// ============================ PATH C: atomic fallback ============================
__global__ void fb_deg_kernel(const int* __restrict__ dst, int E, int* __restrict__ deg) {
    int tid = blockIdx.x * blockDim.x + threadIdx.x;
    int stride = gridDim.x * blockDim.x;
    for (int k = tid; k < E; k += stride) atomicAdd(&deg[dst[k]], 1);
}
__global__ void fb_scatter_kernel(const int* __restrict__ src, const int* __restrict__ dst,
                                  int E, const float* __restrict__ hs, float* __restrict__ s) {
    int tid = blockIdx.x * blockDim.x + threadIdx.x;
    int stride = gridDim.x * blockDim.x;
    const float2* h2 = (const float2*)hs;
    for (int k = tid; k < E; k += stride) {
        int sv = src[k], dv = dst[k];
        float2 m = h2[sv];
        unsafeAtomicAdd(&s[2 * dv], m.x);
        unsafeAtomicAdd(&s[2 * dv + 1], m.y);
    }
}
__global__ void fb_dinv_kernel(const int* __restrict__ deg, int n, float* __restrict__ dinv) {
    int i = blockIdx.x * blockDim.x + threadIdx.x;
    if (i < n) dinv[i] = rsqrtf((float)(deg[i] + 1));
}
__global__ void fb_finalize_kernel(const float* __restrict__ x, const float* __restrict__ s,
                                   const float* __restrict__ hs, const float* __restrict__ dinv,
                                   const float* __restrict__ b, float* __restrict__ out, int n) {
    int i = blockIdx.x * blockDim.x + threadIdx.x;
    if (i >= n) return;
    float di = dinv[i];
    const float2* s2 = (const float2*)s;
    const float2* h2 = (const float2*)hs;
    float2 sv = s2[i];
    float2 hv = h2[i];
    float c0 = di * (sv.x + hv.x) + b[0];
    float c1 = di * (sv.y + hv.y) + b[1];
    float a0 = c0 * ACCEL_SCALE, a1 = c1 * ACCEL_SCALE;
    const float* xr = x + (size_t)i * 5;
    float v0 = fminf(fmaxf(xr[2] + a0, -MAX_VEL), MAX_VEL);
    float v1 = fminf(fmaxf(xr[3] + a1, -MAX_VEL), MAX_VEL);
    float p0 = fminf(fmaxf(xr[0] + v0, -MAX_POS), MAX_POS);
    float p1 = fminf(fmaxf(xr[1] + v1, -MAX_POS), MAX_POS);
    float* o = out + (size_t)i * 5;
    o[0] = p0; o[1] = p1; o[2] = v0; o[3] = v1; o[4] = xr[4];
}

extern "C" void kernel_launch(void* const* d_in, const int* in_sizes, int n_in,
                              void* d_out, int out_size, void* d_ws, size_t ws_size,
                              hipStream_t stream) {
    const float* x    = (const float*)d_in[0];
    const int*   edge = (const int*)d_in[1];
    const float* W    = (const float*)d_in[2];
    const float* b    = (const float*)d_in[3];

    int n = in_sizes[0] / 5;
    int E = in_sizes[1] / 2;
    const int* src = edge;
    const int* dst = edge + E;

    const int BLK = 256;
    int node_blocks = (n + BLK - 1) / BLK;

    // ---------- path A ----------
    int NB_A = (n + ABSIZE - 1) >> ABSHIFT;
    size_t needA = ((size_t)E + (size_t)ANBLK * (NB_A + 1) + 11 * (size_t)n) * 4;
    if (NB_A >= 1 && NB_A < ANBMAX && n <= (1 << 22) && ws_size >= needA) {
        unsigned* packed = (unsigned*)d_ws;
        unsigned* tab    = packed + E;
        int* region      = (int*)(tab + (size_t)ANBLK * (NB_A + 1));
        int* pdeg        = region;                     // [SPLITD][n]   (live: deg->dinv)
        float2* ps       = (float2*)region;            // [SPLITA][n]   (live: acc->final)
        float* dinv      = (float*)(region + 8 * (size_t)n);
        float* hs        = dinv + n;

        int chunk = ((E + ANBLK - 1) / ANBLK + 3) & ~3;

        a_scatter_kernel<<<ANBLK, 256, 0, stream>>>(src, dst, E, NB_A, chunk, tab, packed);
        a_deg_kernel<<<NB_A * SPLITD, 256, 0, stream>>>(packed, tab, E, NB_A, chunk, n, pdeg);
        a_dinv_kernel<<<node_blocks, BLK, 0, stream>>>(pdeg, n, dinv);
        node_pre_kernel<<<node_blocks, BLK, 0, stream>>>(x, W, dinv, hs, n);
        a_acc_kernel<<<NB_A * SPLITA, 256, 0, stream>>>(packed, tab, hs, E, NB_A, chunk, n, ps);
        a_final_kernel<<<node_blocks, BLK, 0, stream>>>(x, ps, hs, dinv, b, (float*)d_out, n);
        return;
    }

    // ---------- path B ----------
    int NB = (n + BSIZE - 1) >> BSHIFT;
    size_t needB = ((size_t)3 * n + 2 * NBMAX) * 4 + (size_t)E * 4;
    if (NB <= NBMAX && ws_size >= needB) {
        float* dinv = (float*)d_ws;
        float* hs   = dinv + n;
        int* ghist  = (int*)(hs + 2 * (size_t)n);
        int* gcursor = ghist + NBMAX;
        unsigned int* packed = (unsigned int*)(gcursor + NBMAX);

        hipMemsetAsync(ghist, 0, NBMAX * sizeof(int), stream);

        hist_kernel<<<512, BLK, 0, stream>>>(dst, E, NB, ghist);
        scan_kernel<<<1, NBMAX, 0, stream>>>(ghist, NB, gcursor);
        scatter_pack_kernel<<<512, BLK, 0, stream>>>(src, dst, E, NB, gcursor, packed);
        dinv_kernel<<<NB, BSIZE, 0, stream>>>(packed, gcursor, ghist, n, dinv);
        node_pre_kernel<<<node_blocks, BLK, 0, stream>>>(x, W, dinv, hs, n);
        acc_finalize_kernel<<<NB, BSIZE, 0, stream>>>(packed, gcursor, ghist, hs, dinv,
                                                      x, b, (float*)d_out, n);
        return;
    }

    // ---------- path C ----------
    {
        float* dinv = (float*)d_ws;
        float* hs   = dinv + n;
        float* s    = hs + 2 * (size_t)n;
        int*   deg  = (int*)(s + 2 * (size_t)n);
        hipMemsetAsync(deg, 0, (size_t)n * sizeof(int), stream);
        hipMemsetAsync(s,   0, (size_t)n * 2 * sizeof(float), stream);
        fb_deg_kernel<<<4096, BLK, 0, stream>>>(dst, E, deg);
        fb_dinv_kernel<<<node_blocks, BLK, 0, stream>>>(deg, n, dinv);
        node_pre_kernel<<<node_blocks, BLK, 0, stream>>>(x, W, dinv, hs, n);
        fb_scatter_kernel<<<4096, BLK, 0, stream>>>(src, dst, E, hs, s);
        fb_finalize_kernel<<<node_blocks, BLK, 0, stream>>>(x, s, hs, dinv, b, (float*)d_out, n);
    }
}

// Round 4
// 260.765 us; speedup vs baseline: 6.7451x; 1.0899x over previous
//
#include <hip/hip_runtime.h>

constexpr float ACCEL_SCALE = 0.01f;
constexpr float MAX_VEL = 0.1f;
constexpr float MAX_POS = 1.0f;

// ============================ PATH A: group-sorted edges ============================
constexpr int GSHIFT = 11;            // 2048 nodes per group
constexpr int GSIZE  = 1 << GSHIFT;
constexpr int SCANW  = 128;           // scan width; requires NG+1 <= SCANW
constexpr int ANBLK  = 512;           // scatter blocks (slices)

// One block sorts its contiguous edge chunk by dst-group, writes packed
// (src<<11 | local_dst) into its own range; per-(slice,group) offsets in tab.
__global__ __launch_bounds__(256) void a_scatter_kernel(
    const int* __restrict__ src, const int* __restrict__ dst,
    int E, int NG, int chunk,
    unsigned* __restrict__ tab, unsigned* __restrict__ packed)
{
    __shared__ int cnt[SCANW];
    __shared__ int tmp[SCANW];
    __shared__ int cur[SCANW];
    int tid = threadIdx.x;
    long long cs64 = (long long)blockIdx.x * chunk;
    int cs = (cs64 > E) ? E : (int)cs64;
    int ce = min(cs + chunk, E);

    if (tid < SCANW) cnt[tid] = 0;
    __syncthreads();

    int nv = (ce - cs) >> 2;
    const int4* d4 = (const int4*)(dst + cs);
    // phase 1: group histogram
    for (int k = tid; k < nv; k += 256) {
        int4 v = d4[k];
        atomicAdd(&cnt[v.x >> GSHIFT], 1);
        atomicAdd(&cnt[v.y >> GSHIFT], 1);
        atomicAdd(&cnt[v.z >> GSHIFT], 1);
        atomicAdd(&cnt[v.w >> GSHIFT], 1);
    }
    for (int i = cs + (nv << 2) + tid; i < ce; i += 256)
        atomicAdd(&cnt[dst[i] >> GSHIFT], 1);
    __syncthreads();

    // phase 2: exclusive scan over SCANW entries
    int v = (tid < SCANW) ? cnt[tid] : 0;
    if (tid < SCANW) tmp[tid] = v;
    __syncthreads();
    for (int off = 1; off < SCANW; off <<= 1) {
        int t = (tid < SCANW && tid >= off) ? tmp[tid - off] : 0;
        __syncthreads();
        if (tid < SCANW) tmp[tid] += t;
        __syncthreads();
    }
    if (tid < SCANW) {
        int base = tmp[tid] - v;
        cur[tid] = base;
        if (tid <= NG) tab[(size_t)blockIdx.x * (NG + 1) + tid] = (unsigned)base;
    }
    __syncthreads();

    // phase 3: scatter into own range
    const int4* s4 = (const int4*)(src + cs);
    for (int k = tid; k < nv; k += 256) {
        int4 dv = d4[k];
        int4 sv = s4[k];
        int p;
        p = atomicAdd(&cur[dv.x >> GSHIFT], 1);
        packed[cs + p] = ((unsigned)sv.x << GSHIFT) | (unsigned)(dv.x & (GSIZE - 1));
        p = atomicAdd(&cur[dv.y >> GSHIFT], 1);
        packed[cs + p] = ((unsigned)sv.y << GSHIFT) | (unsigned)(dv.y & (GSIZE - 1));
        p = atomicAdd(&cur[dv.z >> GSHIFT], 1);
        packed[cs + p] = ((unsigned)sv.z << GSHIFT) | (unsigned)(dv.z & (GSIZE - 1));
        p = atomicAdd(&cur[dv.w >> GSHIFT], 1);
        packed[cs + p] = ((unsigned)sv.w << GSHIFT) | (unsigned)(dv.w & (GSIZE - 1));
    }
    for (int i = cs + (nv << 2) + tid; i < ce; i += 256) {
        int dvv = dst[i], svv = src[i];
        int p = atomicAdd(&cur[dvv >> GSHIFT], 1);
        packed[cs + p] = ((unsigned)svv << GSHIFT) | (unsigned)(dvv & (GSIZE - 1));
    }
}

// per-(group,split) degree count via LDS counters -> pdeg partials
__global__ __launch_bounds__(512) void a_deg_kernel(
    const unsigned* __restrict__ packed, const unsigned* __restrict__ tab,
    int E, int NG, int chunk, int n, int splitShift, int* __restrict__ pdeg)
{
    __shared__ int cnt[GSIZE];
    int g = blockIdx.x >> splitShift;
    int s = blockIdx.x & ((1 << splitShift) - 1);
    for (int t = threadIdx.x; t < GSIZE; t += 512) cnt[t] = 0;
    __syncthreads();
    int wave = threadIdx.x >> 6, lane = threadIdx.x & 63;
    int perSplit = ANBLK >> splitShift;
    int j0 = s * perSplit, jend = j0 + perSplit;
    int j = j0 + wave;
    unsigned nt0 = 0, nt1 = 0;
    if (j < jend) {
        const unsigned* tr = tab + (size_t)j * (NG + 1) + g;
        nt0 = tr[0]; nt1 = tr[1];
    }
    for (; j < jend; j += 8) {
        unsigned t0 = nt0, t1 = nt1;
        int jn = j + 8;
        if (jn < jend) {
            const unsigned* tr = tab + (size_t)jn * (NG + 1) + g;
            nt0 = tr[0]; nt1 = tr[1];
        }
        long long cs64 = (long long)j * chunk;
        int cs = (cs64 > E) ? E : (int)cs64;
        for (unsigned i = t0 + lane; i < t1; i += 64)
            atomicAdd(&cnt[packed[cs + i] & (GSIZE - 1)], 1);
    }
    __syncthreads();
    size_t nb0 = (size_t)g << GSHIFT;
    for (int t = threadIdx.x; t < GSIZE; t += 512) {
        size_t node = nb0 + t;
        if (node < (size_t)n) pdeg[(size_t)s * n + node] = cnt[t];
    }
}

// fused: dinv = rsqrt(1 + sum pdeg), hs = (x @ W) * dinv
__global__ void node_pre_kernel(const float* __restrict__ x, const float* __restrict__ W,
                                const int* __restrict__ pdeg, int n, int nsplit,
                                float* __restrict__ dinv, float* __restrict__ hs) {
    int i = blockIdx.x * blockDim.x + threadIdx.x;
    if (i >= n) return;
    int d = 1;   // self loop
    for (int s = 0; s < nsplit; ++s) d += pdeg[(size_t)s * n + i];
    float di = rsqrtf((float)d);
    dinv[i] = di;
    const float* xr = x + (size_t)i * 5;
    float x0 = xr[0], x1 = xr[1], x2 = xr[2], x3 = xr[3], x4 = xr[4];
    float h0 = x0 * W[0] + x1 * W[2] + x2 * W[4] + x3 * W[6] + x4 * W[8];
    float h1 = x0 * W[1] + x1 * W[3] + x2 * W[5] + x3 * W[7] + x4 * W[9];
    hs[2 * i]     = h0 * di;
    hs[2 * i + 1] = h1 * di;
}

// per-(group,split) LDS accumulate -> ps partials
__global__ __launch_bounds__(512) void a_acc_kernel(
    const unsigned* __restrict__ packed, const unsigned* __restrict__ tab,
    const float* __restrict__ hs, int E, int NG, int chunk, int n, int splitShift,
    float2* __restrict__ ps)
{
    __shared__ float accx[GSIZE];
    __shared__ float accy[GSIZE];
    int g = blockIdx.x >> splitShift;
    int s = blockIdx.x & ((1 << splitShift) - 1);
    for (int t = threadIdx.x; t < GSIZE; t += 512) { accx[t] = 0.f; accy[t] = 0.f; }
    __syncthreads();
    int wave = threadIdx.x >> 6, lane = threadIdx.x & 63;
    int perSplit = ANBLK >> splitShift;
    int j0 = s * perSplit, jend = j0 + perSplit;
    const float2* h2 = (const float2*)hs;
    int j = j0 + wave;
    unsigned nt0 = 0, nt1 = 0;
    if (j < jend) {
        const unsigned* tr = tab + (size_t)j * (NG + 1) + g;
        nt0 = tr[0]; nt1 = tr[1];
    }
    for (; j < jend; j += 8) {
        unsigned t0 = nt0, t1 = nt1;
        int jn = j + 8;
        if (jn < jend) {
            const unsigned* tr = tab + (size_t)jn * (NG + 1) + g;
            nt0 = tr[0]; nt1 = tr[1];
        }
        long long cs64 = (long long)j * chunk;
        int cs = (cs64 > E) ? E : (int)cs64;
        for (unsigned i = t0 + lane; i < t1; i += 64) {
            unsigned p = packed[cs + i];
            float2 m = h2[p >> GSHIFT];
            int ld = p & (GSIZE - 1);
            unsafeAtomicAdd(&accx[ld], m.x);
            unsafeAtomicAdd(&accy[ld], m.y);
        }
    }
    __syncthreads();
    size_t nb0 = (size_t)g << GSHIFT;
    for (int t = threadIdx.x; t < GSIZE; t += 512) {
        size_t node = nb0 + t;
        if (node < (size_t)n) ps[(size_t)s * n + node] = make_float2(accx[t], accy[t]);
    }
}

__global__ void a_final_kernel(const float* __restrict__ x, const float2* __restrict__ ps,
                               const float* __restrict__ hs, const float* __restrict__ dinv,
                               const float* __restrict__ b, float* __restrict__ out,
                               int n, int nsplit) {
    int i = blockIdx.x * blockDim.x + threadIdx.x;
    if (i >= n) return;
    float sx = 0.f, sy = 0.f;
    for (int s = 0; s < nsplit; ++s) {
        float2 v = ps[(size_t)s * n + i];
        sx += v.x; sy += v.y;
    }
    const float2* h2 = (const float2*)hs;
    float di = dinv[i];
    float2 hv = h2[i];
    float c0 = di * (sx + hv.x) + b[0];
    float c1 = di * (sy + hv.y) + b[1];
    float a0 = c0 * ACCEL_SCALE;
    float a1 = c1 * ACCEL_SCALE;
    const float* xr = x + (size_t)i * 5;
    float v0 = fminf(fmaxf(xr[2] + a0, -MAX_VEL), MAX_VEL);
    float v1 = fminf(fmaxf(xr[3] + a1, -MAX_VEL), MAX_VEL);
    float p0 = fminf(fmaxf(xr[0] + v0, -MAX_POS), MAX_POS);
    float p1 = fminf(fmaxf(xr[1] + v1, -MAX_POS), MAX_POS);
    float* o = out + (size_t)i * 5;
    o[0] = p0; o[1] = p1; o[2] = v0; o[3] = v1; o[4] = xr[4];
}

// ============================ PATH B: round-2 pipeline (fallback) ============================
constexpr int BSHIFT = 8;
constexpr int BSIZE  = 1 << BSHIFT;
constexpr int NBMAX  = 1024;

__global__ void hist_kernel(const int* __restrict__ dst, int E, int NB,
                            int* __restrict__ ghist) {
    __shared__ int lh[NBMAX];
    for (int t = threadIdx.x; t < NB; t += blockDim.x) lh[t] = 0;
    __syncthreads();
    int chunk = ((E + gridDim.x - 1) / gridDim.x + 3) & ~3;
    int start = blockIdx.x * chunk;
    int end = min(start + chunk, E);
    if (start < end) {
        int nvec = (end - start) >> 2;
        const int4* d4 = (const int4*)(dst + start);
        for (int k = threadIdx.x; k < nvec; k += blockDim.x) {
            int4 v = d4[k];
            atomicAdd(&lh[v.x >> BSHIFT], 1);
            atomicAdd(&lh[v.y >> BSHIFT], 1);
            atomicAdd(&lh[v.z >> BSHIFT], 1);
            atomicAdd(&lh[v.w >> BSHIFT], 1);
        }
        for (int i = start + (nvec << 2) + threadIdx.x; i < end; i += blockDim.x)
            atomicAdd(&lh[dst[i] >> BSHIFT], 1);
    }
    __syncthreads();
    for (int t = threadIdx.x; t < NB; t += blockDim.x) {
        int c = lh[t];
        if (c) atomicAdd(&ghist[t], c);
    }
}

__global__ void scan_kernel(const int* __restrict__ ghist, int NB,
                            int* __restrict__ gcursor) {
    __shared__ int tmp[NBMAX];
    int tid = threadIdx.x;
    int v = (tid < NB) ? ghist[tid] : 0;
    tmp[tid] = v;
    __syncthreads();
    for (int off = 1; off < NBMAX; off <<= 1) {
        int t = (tid >= off) ? tmp[tid - off] : 0;
        __syncthreads();
        tmp[tid] += t;
        __syncthreads();
    }
    if (tid < NB) gcursor[tid] = tmp[tid] - v;
}

__global__ void scatter_pack_kernel(const int* __restrict__ src, const int* __restrict__ dst,
                                    int E, int NB, int* __restrict__ gcursor,
                                    unsigned int* __restrict__ packed) {
    __shared__ int lh[NBMAX];
    for (int t = threadIdx.x; t < NB; t += blockDim.x) lh[t] = 0;
    __syncthreads();
    int chunk = ((E + gridDim.x - 1) / gridDim.x + 3) & ~3;
    int start = blockIdx.x * chunk;
    int end = min(start + chunk, E);
    int nvec = (start < end) ? ((end - start) >> 2) : 0;
    const int4* d4 = (const int4*)(dst + start);
    const int4* s4 = (const int4*)(src + start);
    if (start < end) {
        for (int k = threadIdx.x; k < nvec; k += blockDim.x) {
            int4 v = d4[k];
            atomicAdd(&lh[v.x >> BSHIFT], 1);
            atomicAdd(&lh[v.y >> BSHIFT], 1);
            atomicAdd(&lh[v.z >> BSHIFT], 1);
            atomicAdd(&lh[v.w >> BSHIFT], 1);
        }
        for (int i = start + (nvec << 2) + threadIdx.x; i < end; i += blockDim.x)
            atomicAdd(&lh[dst[i] >> BSHIFT], 1);
    }
    __syncthreads();
    for (int t = threadIdx.x; t < NB; t += blockDim.x) {
        int c = lh[t];
        lh[t] = c ? atomicAdd(&gcursor[t], c) : 0;
    }
    __syncthreads();
    if (start < end) {
        for (int k = threadIdx.x; k < nvec; k += blockDim.x) {
            int4 dv = d4[k];
            int4 sv = s4[k];
            int p;
            p = atomicAdd(&lh[dv.x >> BSHIFT], 1);
            packed[p] = ((unsigned)sv.x << BSHIFT) | (unsigned)(dv.x & (BSIZE - 1));
            p = atomicAdd(&lh[dv.y >> BSHIFT], 1);
            packed[p] = ((unsigned)sv.y << BSHIFT) | (unsigned)(dv.y & (BSIZE - 1));
            p = atomicAdd(&lh[dv.z >> BSHIFT], 1);
            packed[p] = ((unsigned)sv.z << BSHIFT) | (unsigned)(dv.z & (BSIZE - 1));
            p = atomicAdd(&lh[dv.w >> BSHIFT], 1);
            packed[p] = ((unsigned)sv.w << BSHIFT) | (unsigned)(dv.w & (BSIZE - 1));
        }
        for (int i = start + (nvec << 2) + threadIdx.x; i < end; i += blockDim.x) {
            int dv = dst[i], sv = src[i];
            int p = atomicAdd(&lh[dv >> BSHIFT], 1);
            packed[p] = ((unsigned)sv << BSHIFT) | (unsigned)(dv & (BSIZE - 1));
        }
    }
}

__global__ void dinv_kernel(const unsigned int* __restrict__ packed,
                            const int* __restrict__ gcursor, const int* __restrict__ ghist,
                            int n, float* __restrict__ dinv) {
    __shared__ int cnt[BSIZE];
    int bk = blockIdx.x;
    cnt[threadIdx.x] = 0;
    __syncthreads();
    int end = gcursor[bk];
    int start = end - ghist[bk];
    for (int i = start + threadIdx.x; i < end; i += blockDim.x)
        atomicAdd(&cnt[packed[i] & (BSIZE - 1)], 1);
    __syncthreads();
    int node = (bk << BSHIFT) + threadIdx.x;
    if (node < n)
        dinv[node] = rsqrtf((float)(cnt[threadIdx.x] + 1));
}

__global__ void b_node_pre_kernel(const float* __restrict__ x, const float* __restrict__ W,
                                  const float* __restrict__ dinv, float* __restrict__ hs, int n) {
    int i = blockIdx.x * blockDim.x + threadIdx.x;
    if (i >= n) return;
    const float* xr = x + (size_t)i * 5;
    float x0 = xr[0], x1 = xr[1], x2 = xr[2], x3 = xr[3], x4 = xr[4];
    float h0 = x0 * W[0] + x1 * W[2] + x2 * W[4] + x3 * W[6] + x4 * W[8];
    float h1 = x0 * W[1] + x1 * W[3] + x2 * W[5] + x3 * W[7] + x4 * W[9];
    float di = dinv[i];
    hs[2 * i]     = h0 * di;
    hs[2 * i + 1] = h1 * di;
}

__global__ void acc_finalize_kernel(const unsigned int* __restrict__ packed,
                                    const int* __restrict__ gcursor, const int* __restrict__ ghist,
                                    const float* __restrict__ hs, const float* __restrict__ dinv,
                                    const float* __restrict__ x, const float* __restrict__ b,
                                    float* __restrict__ out, int n) {
    __shared__ float accx[BSIZE];
    __shared__ float accy[BSIZE];
    int bk = blockIdx.x;
    accx[threadIdx.x] = 0.f;
    accy[threadIdx.x] = 0.f;
    __syncthreads();
    int end = gcursor[bk];
    int start = end - ghist[bk];
    const float2* h2 = (const float2*)hs;
    for (int i = start + threadIdx.x; i < end; i += blockDim.x) {
        unsigned int p = packed[i];
        float2 m = h2[p >> BSHIFT];
        int ld = p & (BSIZE - 1);
        unsafeAtomicAdd(&accx[ld], m.x);
        unsafeAtomicAdd(&accy[ld], m.y);
    }
    __syncthreads();
    int node = (bk << BSHIFT) + threadIdx.x;
    if (node >= n) return;
    float di = dinv[node];
    float2 hv = h2[node];
    float c0 = di * (accx[threadIdx.x] + hv.x) + b[0];
    float c1 = di * (accy[threadIdx.x] + hv.y) + b[1];
    float a0 = c0 * ACCEL_SCALE;
    float a1 = c1 * ACCEL_SCALE;
    const float* xr = x + (size_t)node * 5;
    float v0 = fminf(fmaxf(xr[2] + a0, -MAX_VEL), MAX_VEL);
    float v1 = fminf(fmaxf(xr[3] + a1, -MAX_VEL), MAX_VEL);
    float p0 = fminf(fmaxf(xr[0] + v0, -MAX_POS), MAX_POS);
    float p1 = fminf(fmaxf(xr[1] + v1, -MAX_POS), MAX_POS);
    float* o = out + (size_t)node * 5;
    o[0] = p0; o[1] = p1; o[2] = v0; o[3] = v1; o[4] = xr[4];
}

// ============================ PATH C: atomic fallback ============================
__global__ void fb_deg_kernel(const int* __restrict__ dst, int E, int* __restrict__ deg) {
    int tid = blockIdx.x * blockDim.x + threadIdx.x;
    int stride = gridDim.x * blockDim.x;
    for (int k = tid; k < E; k += stride) atomicAdd(&deg[dst[k]], 1);
}
__global__ void fb_scatter_kernel(const int* __restrict__ src, const int* __restrict__ dst,
                                  int E, const float* __restrict__ hs, float* __restrict__ s) {
    int tid = blockIdx.x * blockDim.x + threadIdx.x;
    int stride = gridDim.x * blockDim.x;
    const float2* h2 = (const float2*)hs;
    for (int k = tid; k < E; k += stride) {
        int sv = src[k], dv = dst[k];
        float2 m = h2[sv];
        unsafeAtomicAdd(&s[2 * dv], m.x);
        unsafeAtomicAdd(&s[2 * dv + 1], m.y);
    }
}
__global__ void fb_dinv_kernel(const int* __restrict__ deg, int n, float* __restrict__ dinv) {
    int i = blockIdx.x * blockDim.x + threadIdx.x;
    if (i < n) dinv[i] = rsqrtf((float)(deg[i] + 1));
}
__global__ void fb_finalize_kernel(const float* __restrict__ x, const float* __restrict__ s,
                                   const float* __restrict__ hs, const float* __restrict__ dinv,
                                   const float* __restrict__ b, float* __restrict__ out, int n) {
    int i = blockIdx.x * blockDim.x + threadIdx.x;
    if (i >= n) return;
    float di = dinv[i];
    const float2* s2 = (const float2*)s;
    const float2* h2 = (const float2*)hs;
    float2 sv = s2[i];
    float2 hv = h2[i];
    float c0 = di * (sv.x + hv.x) + b[0];
    float c1 = di * (sv.y + hv.y) + b[1];
    float a0 = c0 * ACCEL_SCALE, a1 = c1 * ACCEL_SCALE;
    const float* xr = x + (size_t)i * 5;
    float v0 = fminf(fmaxf(xr[2] + a0, -MAX_VEL), MAX_VEL);
    float v1 = fminf(fmaxf(xr[3] + a1, -MAX_VEL), MAX_VEL);
    float p0 = fminf(fmaxf(xr[0] + v0, -MAX_POS), MAX_POS);
    float p1 = fminf(fmaxf(xr[1] + v1, -MAX_POS), MAX_POS);
    float* o = out + (size_t)i * 5;
    o[0] = p0; o[1] = p1; o[2] = v0; o[3] = v1; o[4] = xr[4];
}

extern "C" void kernel_launch(void* const* d_in, const int* in_sizes, int n_in,
                              void* d_out, int out_size, void* d_ws, size_t ws_size,
                              hipStream_t stream) {
    const float* x    = (const float*)d_in[0];
    const int*   edge = (const int*)d_in[1];
    const float* W    = (const float*)d_in[2];
    const float* b    = (const float*)d_in[3];

    int n = in_sizes[0] / 5;
    int E = in_sizes[1] / 2;
    const int* src = edge;
    const int* dst = edge + E;

    const int BLK = 256;
    int node_blocks = (n + BLK - 1) / BLK;

    // ---------- path A ----------
    int NG = (n + GSIZE - 1) >> GSHIFT;
    bool okA = (NG >= 1) && (NG + 1 <= SCANW) && (n <= (1 << 21)) && (E >= 8);
    if (okA) {
        size_t base = (size_t)E * 4                      // packed
                    + (size_t)ANBLK * (NG + 1) * 4       // tab
                    + (size_t)n * 4                      // dinv
                    + (size_t)n * 8;                     // hs
        size_t need8 = base + (size_t)8 * n * 8;         // ps at split 8
        size_t need4 = base + (size_t)4 * n * 8;         // ps at split 4
        int splitShift = 0;
        if (ws_size >= need8)      splitShift = 3;
        else if (ws_size >= need4) splitShift = 2;
        if (splitShift) {
            int split = 1 << splitShift;
            unsigned* packed = (unsigned*)d_ws;
            unsigned* tab    = packed + E;
            int* region      = (int*)(tab + (size_t)ANBLK * (NG + 1));
            int* pdeg        = region;            // [split][n] ints (live: deg->node_pre)
            float2* ps       = (float2*)region;   // [split][n] float2 (live: acc->final)
            float* dinv      = (float*)(region + (size_t)split * n * 2);
            float* hs        = dinv + n;

            int chunk = ((E + ANBLK - 1) / ANBLK + 3) & ~3;

            a_scatter_kernel<<<ANBLK, 256, 0, stream>>>(src, dst, E, NG, chunk, tab, packed);
            a_deg_kernel<<<NG << splitShift, 512, 0, stream>>>(packed, tab, E, NG, chunk, n,
                                                               splitShift, pdeg);
            node_pre_kernel<<<node_blocks, BLK, 0, stream>>>(x, W, pdeg, n, split, dinv, hs);
            a_acc_kernel<<<NG << splitShift, 512, 0, stream>>>(packed, tab, hs, E, NG, chunk, n,
                                                               splitShift, ps);
            a_final_kernel<<<node_blocks, BLK, 0, stream>>>(x, ps, hs, dinv, b,
                                                            (float*)d_out, n, split);
            return;
        }
    }

    // ---------- path B ----------
    int NB = (n + BSIZE - 1) >> BSHIFT;
    size_t needB = ((size_t)3 * n + 2 * NBMAX) * 4 + (size_t)E * 4;
    if (NB <= NBMAX && ws_size >= needB) {
        float* dinv = (float*)d_ws;
        float* hs   = dinv + n;
        int* ghist  = (int*)(hs + 2 * (size_t)n);
        int* gcursor = ghist + NBMAX;
        unsigned int* packed = (unsigned int*)(gcursor + NBMAX);

        hipMemsetAsync(ghist, 0, NBMAX * sizeof(int), stream);

        hist_kernel<<<512, BLK, 0, stream>>>(dst, E, NB, ghist);
        scan_kernel<<<1, NBMAX, 0, stream>>>(ghist, NB, gcursor);
        scatter_pack_kernel<<<512, BLK, 0, stream>>>(src, dst, E, NB, gcursor, packed);
        dinv_kernel<<<NB, BSIZE, 0, stream>>>(packed, gcursor, ghist, n, dinv);
        b_node_pre_kernel<<<node_blocks, BLK, 0, stream>>>(x, W, dinv, hs, n);
        acc_finalize_kernel<<<NB, BSIZE, 0, stream>>>(packed, gcursor, ghist, hs, dinv,
                                                      x, b, (float*)d_out, n);
        return;
    }

    // ---------- path C ----------
    {
        float* dinv = (float*)d_ws;
        float* hs   = dinv + n;
        float* s    = hs + 2 * (size_t)n;
        int*   deg  = (int*)(s + 2 * (size_t)n);
        hipMemsetAsync(deg, 0, (size_t)n * sizeof(int), stream);
        hipMemsetAsync(s,   0, (size_t)n * 2 * sizeof(float), stream);
        fb_deg_kernel<<<4096, BLK, 0, stream>>>(dst, E, deg);
        fb_dinv_kernel<<<node_blocks, BLK, 0, stream>>>(deg, n, dinv);
        b_node_pre_kernel<<<node_blocks, BLK, 0, stream>>>(x, W, dinv, hs, n);
        fb_scatter_kernel<<<4096, BLK, 0, stream>>>(src, dst, E, hs, s);
        fb_finalize_kernel<<<node_blocks, BLK, 0, stream>>>(x, s, hs, dinv, b, (float*)d_out, n);
    }
}